// Round 1
// 149.247 us; speedup vs baseline: 1.0481x; 1.0481x over previous
//
#include <hip/hip_runtime.h>

#define LN_EPS 1e-5f

__device__ __forceinline__ float dot8(float4 a0, float4 a1, float4 b0, float4 b1) {
    return a0.x * b0.x + a0.y * b0.y + a0.z * b0.z + a0.w * b0.w +
           a1.x * b1.x + a1.y * b1.y + a1.z * b1.z + a1.w * b1.w;
}

// ---------------------------------------------------------------------------
// Kernel 1: embed + pos + row attention (64 bins) + residual + LN
// 256 blocks x 1024 threads (16 waves/CU = 50% occupancy, was 4 waves/CU).
// QKV: 6 outputs/thread. Attention: key-dim split 4-ways, shuffle merge.
// ---------------------------------------------------------------------------
__global__ __launch_bounds__(1024) void k_row(
    const float* __restrict__ ctcf, const float* __restrict__ hac,
    const float* __restrict__ me1,  const float* __restrict__ me3,
    const float* __restrict__ ew,   const float* __restrict__ eb,
    const float* __restrict__ pe,
    const float* __restrict__ w_in, const float* __restrict__ b_in,
    const float* __restrict__ w_out,const float* __restrict__ b_out,
    const float* __restrict__ ln_g, const float* __restrict__ ln_b,
    float* __restrict__ msaR)
{
    __shared__ float sx[64][33];        // x tile (residual source)
    __shared__ float sqkv[64 * 100];    // qkv rows, stride 100 (16B-aligned)
    __shared__ float so[64][33];        // attention output
    __shared__ float smean[64], srstd[64];

    const int blk = blockIdx.x;          // b*4 + s
    const int s   = blk & 3;
    const int b   = blk >> 2;
    const int tid = threadIdx.x;

    const float* chip = (s == 0) ? ctcf : (s == 1) ? hac : (s == 2) ? me1 : me3;

    for (int n = tid; n < 2048; n += 1024) {
        int l = n >> 5, c = n & 31;
        sx[l][c] = chip[b * 64 + l] * ew[c] + eb[c] + pe[l * 32 + c];
    }
    __syncthreads();

    const int l  = tid & 63;
    const int cg = tid >> 6;             // wave id 0..15 -> wave-uniform

    // qkv[l][cc] = x[l]·w_in[cc] + b_in[cc]; weight row from global (uniform)
    {
        float xr[32];
#pragma unroll
        for (int c = 0; c < 32; ++c) xr[c] = sx[l][c];
#pragma unroll
        for (int i = 0; i < 6; ++i) {
            int cc = i * 16 + cg;        // 0..95
            const float4* wr4 = (const float4*)&w_in[cc * 32];
            float acc = b_in[cc];
#pragma unroll
            for (int c4 = 0; c4 < 8; ++c4) {
                float4 wv = wr4[c4];
                acc += xr[c4 * 4 + 0] * wv.x + xr[c4 * 4 + 1] * wv.y +
                       xr[c4 * 4 + 2] * wv.z + xr[c4 * 4 + 3] * wv.w;
            }
            sqkv[l * 100 + cc] = acc;
        }
    }
    __syncthreads();

    // attention: thread (h = tid>>8, la = (tid>>2)&63, kc = tid&3)
    // kc in lane bits 0-1 -> 4-way key split merged with shfl_xor butterfly
    {
        const int h  = tid >> 8;
        const int la = (tid >> 2) & 63;
        const int kc = tid & 3;
        const float4* qp = (const float4*)&sqkv[la * 100 + h * 8];
        float4 q0 = qp[0], q1 = qp[1];
        const float scale = 0.35355339059327373f;  // 1/sqrt(8)
        float mrun = -1e30f, denom = 0.f, a[8];
#pragma unroll
        for (int dd = 0; dd < 8; ++dd) a[dd] = 0.f;
#pragma unroll
        for (int jj = 0; jj < 16; ++jj) {
            const int j = kc * 16 + jj;
            const float4* kp = (const float4*)&sqkv[j * 100 + 32 + h * 8];
            float sc = dot8(q0, q1, kp[0], kp[1]) * scale;
            const float4* vp = (const float4*)&sqkv[j * 100 + 64 + h * 8];
            float4 v0 = vp[0], v1 = vp[1];
            float mnew = fmaxf(mrun, sc);
            float corr = __expf(mrun - mnew);
            float w = __expf(sc - mnew);
            denom = denom * corr + w;
            a[0] = a[0] * corr + w * v0.x;  a[1] = a[1] * corr + w * v0.y;
            a[2] = a[2] * corr + w * v0.z;  a[3] = a[3] * corr + w * v0.w;
            a[4] = a[4] * corr + w * v1.x;  a[5] = a[5] * corr + w * v1.y;
            a[6] = a[6] * corr + w * v1.z;  a[7] = a[7] * corr + w * v1.w;
            mrun = mnew;
        }
        // merge the 4 partial softmaxes (lanes differing in bits 0-1)
#pragma unroll
        for (int off = 1; off <= 2; off <<= 1) {
            float mo = __shfl_xor(mrun, off, 64);
            float dn = __shfl_xor(denom, off, 64);
            float mn = fmaxf(mrun, mo);
            float c1 = __expf(mrun - mn);
            float c2 = __expf(mo - mn);
            denom = denom * c1 + dn * c2;
#pragma unroll
            for (int dd = 0; dd < 8; ++dd) {
                float ao = __shfl_xor(a[dd], off, 64);
                a[dd] = a[dd] * c1 + ao * c2;
            }
            mrun = mn;
        }
        float inv = 1.f / denom;
        // lane kc writes columns 2kc, 2kc+1 (static reg indexing only)
        float r0, r1;
        if      (kc == 0) { r0 = a[0]; r1 = a[1]; }
        else if (kc == 1) { r0 = a[2]; r1 = a[3]; }
        else if (kc == 2) { r0 = a[4]; r1 = a[5]; }
        else              { r0 = a[6]; r1 = a[7]; }
        so[la][h * 8 + kc * 2 + 0] = r0 * inv;
        so[la][h * 8 + kc * 2 + 1] = r1 * inv;
    }
    __syncthreads();

    // out proj + residual -> sqkv cols 0..31 (2 outputs/thread)
    {
        float orow[32];
#pragma unroll
        for (int k = 0; k < 32; ++k) orow[k] = so[l][k];
#pragma unroll
        for (int i = 0; i < 2; ++i) {
            int c = i * 16 + cg;
            const float4* wr4 = (const float4*)&w_out[c * 32];
            float acc = b_out[c] + sx[l][c];   // residual re-read from LDS
#pragma unroll
            for (int k4 = 0; k4 < 8; ++k4) {
                float4 wv = wr4[k4];
                acc += orow[k4 * 4 + 0] * wv.x + orow[k4 * 4 + 1] * wv.y +
                       orow[k4 * 4 + 2] * wv.z + orow[k4 * 4 + 3] * wv.w;
            }
            sqkv[l * 100 + c] = acc;
        }
    }
    __syncthreads();

    if (tid < 64) {
        float mu = 0.f;
#pragma unroll
        for (int c = 0; c < 32; ++c) mu += sqkv[tid * 100 + c];
        mu *= (1.f / 32.f);
        float var = 0.f;
#pragma unroll
        for (int c = 0; c < 32; ++c) { float d = sqkv[tid * 100 + c] - mu; var += d * d; }
        var *= (1.f / 32.f);
        smean[tid] = mu;
        srstd[tid] = rsqrtf(var + LN_EPS);
    }
    __syncthreads();

    float* outp = msaR + blk * 2048;     // (B,S,Lb,C)
    for (int n = tid; n < 2048; n += 1024) {
        int ll = n >> 5, c = n & 31;
        outp[n] = (sqkv[ll * 100 + c] - smean[ll]) * srstd[ll] * ln_g[c] + ln_b[c];
    }
}

// ---------------------------------------------------------------------------
// Kernel 2: column attention (4 tracks) + residual + LN + track mean + norm
// 256 blocks x 1024 threads (16 waves/CU). Attention phase is tiny (4 keys),
// kept on first 256 threads.
// ---------------------------------------------------------------------------
__global__ __launch_bounds__(1024) void k_col(
    const float* __restrict__ msaR,
    const float* __restrict__ w_in, const float* __restrict__ b_in,
    const float* __restrict__ w_out,const float* __restrict__ b_out,
    const float* __restrict__ ln_g, const float* __restrict__ ln_b,
    float* __restrict__ m_out, float* __restrict__ nrm_out)
{
    __shared__ float sx[64][33];        // rows keyed s*16+lo
    __shared__ float sqkv[64 * 100];    // rows keyed r = lo*4+s
    __shared__ float so[64][33];        // rows keyed r
    __shared__ float smean2[64], srstd2[64];
    __shared__ float smv[16][33];

    const int bx = blockIdx.x;           // 64 b x 4 chunks
    const int b  = bx >> 2;
    const int l0 = (bx & 3) * 16;
    const int tid = threadIdx.x;

    for (int n = tid; n < 2048; n += 1024) {
        int s = n >> 9, lo = (n >> 5) & 15, c = n & 31;
        sx[s * 16 + lo][c] = msaR[((b * 4 + s) * 64 + l0 + lo) * 32 + c];
    }
    __syncthreads();

    const int r  = tid & 63;
    const int sS = r & 3, lo = r >> 2;
    const int cg = tid >> 6;             // 0..15

    {
        float xr[32];
#pragma unroll
        for (int c = 0; c < 32; ++c) xr[c] = sx[sS * 16 + lo][c];
#pragma unroll
        for (int i = 0; i < 6; ++i) {
            int cc = i * 16 + cg;
            const float4* wr4 = (const float4*)&w_in[cc * 32];
            float acc = b_in[cc];
#pragma unroll
            for (int c4 = 0; c4 < 8; ++c4) {
                float4 wv = wr4[c4];
                acc += xr[c4 * 4 + 0] * wv.x + xr[c4 * 4 + 1] * wv.y +
                       xr[c4 * 4 + 2] * wv.z + xr[c4 * 4 + 3] * wv.w;
            }
            sqkv[r * 100 + cc] = acc;
        }
    }
    __syncthreads();

    // attention over 4 tracks: (la = tid>>4, h = (tid>>2)&3, ia = tid&3)
    if (tid < 256) {
        const int la = tid >> 4, h = (tid >> 2) & 3, ia = tid & 3;
        const float scale = 0.35355339059327373f;
        const float4* qp = (const float4*)&sqkv[(la * 4 + ia) * 100 + h * 8];
        float4 q0 = qp[0], q1 = qp[1];
        float sc[4];
        float mx = -1e30f;
#pragma unroll
        for (int jj = 0; jj < 4; ++jj) {
            const float4* kp = (const float4*)&sqkv[(la * 4 + jj) * 100 + 32 + h * 8];
            sc[jj] = dot8(q0, q1, kp[0], kp[1]) * scale;
            mx = fmaxf(mx, sc[jj]);
        }
        float den = 0.f;
#pragma unroll
        for (int jj = 0; jj < 4; ++jj) { sc[jj] = __expf(sc[jj] - mx); den += sc[jj]; }
        float inv = 1.f / den;
        float a[8];
#pragma unroll
        for (int dd = 0; dd < 8; ++dd) a[dd] = 0.f;
#pragma unroll
        for (int jj = 0; jj < 4; ++jj) {
            const float4* vp = (const float4*)&sqkv[(la * 4 + jj) * 100 + 64 + h * 8];
            float4 v0 = vp[0], v1 = vp[1];
            float wgt = sc[jj];
            a[0] += wgt * v0.x;  a[1] += wgt * v0.y;
            a[2] += wgt * v0.z;  a[3] += wgt * v0.w;
            a[4] += wgt * v1.x;  a[5] += wgt * v1.y;
            a[6] += wgt * v1.z;  a[7] += wgt * v1.w;
        }
#pragma unroll
        for (int dd = 0; dd < 8; ++dd) so[la * 4 + ia][h * 8 + dd] = a[dd] * inv;
    }
    __syncthreads();

    {
        float orow[32];
#pragma unroll
        for (int k = 0; k < 32; ++k) orow[k] = so[r][k];
#pragma unroll
        for (int i = 0; i < 2; ++i) {
            int c = i * 16 + cg;
            const float4* wr4 = (const float4*)&w_out[c * 32];
            float acc = b_out[c] + sx[sS * 16 + lo][c];
#pragma unroll
            for (int k4 = 0; k4 < 8; ++k4) {
                float4 wv = wr4[k4];
                acc += orow[k4 * 4 + 0] * wv.x + orow[k4 * 4 + 1] * wv.y +
                       orow[k4 * 4 + 2] * wv.z + orow[k4 * 4 + 3] * wv.w;
            }
            sqkv[r * 100 + c] = acc;
        }
    }
    __syncthreads();

    if (tid < 64) {
        float mu = 0.f;
#pragma unroll
        for (int c = 0; c < 32; ++c) mu += sqkv[tid * 100 + c];
        mu *= (1.f / 32.f);
        float var = 0.f;
#pragma unroll
        for (int c = 0; c < 32; ++c) { float d = sqkv[tid * 100 + c] - mu; var += d * d; }
        var *= (1.f / 32.f);
        smean2[tid] = mu;
        srstd2[tid] = rsqrtf(var + LN_EPS);
    }
    __syncthreads();

    if (tid < 512) {                     // 512 = 16 lo x 32 c
        int loo = tid >> 5, c = tid & 31;
        float acc = 0.f;
#pragma unroll
        for (int ss = 0; ss < 4; ++ss) {
            int rr = loo * 4 + ss;
            acc += (sqkv[rr * 100 + c] - smean2[rr]) * srstd2[rr];
        }
        float mval = 0.25f * acc * ln_g[c] + ln_b[c];
        m_out[(b * 64 + l0 + loo) * 32 + c] = mval;
        smv[loo][c] = mval * mval;
    }
    __syncthreads();

    if (tid < 16) {
        float sum = 0.f;
#pragma unroll
        for (int c = 0; c < 32; ++c) sum += smv[tid][c];
        nrm_out[b * 64 + l0 + tid] = sqrtf(sum);
    }
}

// ---------------------------------------------------------------------------
// Kernel 3: factorized outer-product + proj + LN + SiLU + transpose
// feat[b,i,j,cp] = (T_i[cp]·m_j)/(|m_i||m_j|) + pb;  T_i = pw·m_i
// 512 blocks (b x 8 i-chunks of 8) x 512 threads -> 2 blocks/CU = 16 waves/CU.
// T phase: 1 rem/thread (pw slice = 32 regs). Out phase: wave w -> il = w.
// ---------------------------------------------------------------------------
__global__ __launch_bounds__(512, 4) void k_pair(
    const float* __restrict__ m, const float* __restrict__ nrm,
    const float* __restrict__ pw, const float* __restrict__ pb,
    const float* __restrict__ pg, const float* __restrict__ pbeta,
    float* __restrict__ out)
{
    __shared__ float smj[64][36];       // stride 36 -> rows 16B-aligned
    __shared__ float sT[8 * 520];       // [il][rem], stride 520 (16B-aligned)
    __shared__ float snj[64];
    __shared__ float sbias[16], sgam[16], sbet[16];

    const int bx = blockIdx.x;          // 64 b x 8 i-chunks
    const int b  = bx >> 3;
    const int i0 = (bx & 7) * 8;
    const int tid = threadIdx.x;
    const int lane = tid & 63, w = tid >> 6;   // w = 0..7

    // preload this thread's pw rem-row into regs (global, coalesced, L2-hot)
    const int rem = tid;                 // rem = cp*32+d, one per thread
    const float* pwp = pw + (rem >> 5) * 1024 + (rem & 31);
    float w0[32];
#pragma unroll
    for (int c = 0; c < 32; ++c) w0[c] = pwp[c * 32];

    const float* mb = m + b * 2048;
    for (int n = tid; n < 2048; n += 512) smj[n >> 5][n & 31] = mb[n];
    if (tid < 64) snj[tid] = nrm[b * 64 + tid];
    if (tid < 16) {
        sbias[tid] = pb[tid];
        sgam[tid]  = pg[tid];
        sbet[tid]  = pbeta[tid];
    }
    __syncthreads();

    // T phase: every thread computes T[il][rem] for il = 0..7
#pragma unroll
    for (int il = 0; il < 8; ++il) {
        const float4* mr4 = (const float4*)&smj[i0 + il][0];  // b128 broadcast
        float a0 = 0.f;
#pragma unroll
        for (int c4 = 0; c4 < 8; ++c4) {
            float4 mv = mr4[c4];
            a0 += mv.x * w0[c4 * 4 + 0] + mv.y * w0[c4 * 4 + 1] +
                  mv.z * w0[c4 * 4 + 2] + mv.w * w0[c4 * 4 + 3];
        }
        sT[il * 520 + rem] = a0;        // lane-distinct banks, conflict-free
    }
    __syncthreads();

    // out phase: lane = j; wave w handles il = w
    const int j = lane;
    float mj[32];
    {
        const float4* mjp = (const float4*)&smj[j][0];
#pragma unroll
        for (int d4 = 0; d4 < 8; ++d4) {
            float4 t = mjp[d4];
            mj[d4 * 4 + 0] = t.x;  mj[d4 * 4 + 1] = t.y;
            mj[d4 * 4 + 2] = t.z;  mj[d4 * 4 + 3] = t.w;
        }
    }
    const float nj = snj[j];

    {
        const int il = w;
        const int ig = i0 + il;
        const float invn = 1.f / fmaxf(snj[ig] * nj, 1e-6f);
        float f[16];
#pragma unroll
        for (int cp = 0; cp < 16; ++cp) {
            const float4* tr = (const float4*)&sT[il * 520 + cp * 32]; // b128 bcast
            float acc = 0.f;
#pragma unroll
            for (int d4 = 0; d4 < 8; ++d4) {
                float4 tv = tr[d4];
                acc += tv.x * mj[d4 * 4 + 0] + tv.y * mj[d4 * 4 + 1] +
                       tv.z * mj[d4 * 4 + 2] + tv.w * mj[d4 * 4 + 3];
            }
            f[cp] = acc * invn + sbias[cp];
        }
        float mu = 0.f;
#pragma unroll
        for (int cp = 0; cp < 16; ++cp) mu += f[cp];
        mu *= (1.f / 16.f);
        float var = 0.f;
#pragma unroll
        for (int cp = 0; cp < 16; ++cp) { float d = f[cp] - mu; var += d * d; }
        var *= (1.f / 16.f);
        const float rstd = rsqrtf(var + LN_EPS);
#pragma unroll
        for (int cp = 0; cp < 16; ++cp) {
            float v = (f[cp] - mu) * rstd * sgam[cp] + sbet[cp];
            float sl = v / (1.f + __expf(-v));
            out[((b * 16 + cp) * 64 + ig) * 64 + j] = sl;
        }
    }
}

// ---------------------------------------------------------------------------
extern "C" void kernel_launch(void* const* d_in, const int* in_sizes, int n_in,
                              void* d_out, int out_size, void* d_ws, size_t ws_size,
                              hipStream_t stream) {
    const float* ctcf  = (const float*)d_in[0];
    const float* hac   = (const float*)d_in[1];
    const float* me1   = (const float*)d_in[2];
    const float* me3   = (const float*)d_in[3];
    const float* ew    = (const float*)d_in[4];
    const float* ebias = (const float*)d_in[5];
    const float* pe    = (const float*)d_in[6];
    const float* riw   = (const float*)d_in[7];
    const float* rib   = (const float*)d_in[8];
    const float* row_  = (const float*)d_in[9];
    const float* rob   = (const float*)d_in[10];
    const float* rlg   = (const float*)d_in[11];
    const float* rlb   = (const float*)d_in[12];
    const float* ciw   = (const float*)d_in[13];
    const float* cib   = (const float*)d_in[14];
    const float* cow   = (const float*)d_in[15];
    const float* cob   = (const float*)d_in[16];
    const float* clg   = (const float*)d_in[17];
    const float* clb   = (const float*)d_in[18];
    const float* pw    = (const float*)d_in[19];
    const float* pb    = (const float*)d_in[20];
    const float* pg    = (const float*)d_in[21];
    const float* pbt   = (const float*)d_in[22];

    float* out = (float*)d_out;

    // msaR (2 MB) borrows d_out (16 MB f32): fully consumed by k_col before
    // k_pair writes out (serial stream). m + norms in ws (~528 KB).
    float* msaR = (float*)d_out;
    float* mbuf = (float*)d_ws;                  // 64*64*32 floats
    float* nbuf = mbuf + 64 * 64 * 32;           // 64*64 floats

    k_row<<<256, 1024, 0, stream>>>(ctcf, hac, me1, me3, ew, ebias, pe,
                                    riw, rib, row_, rob, rlg, rlb, msaR);
    k_col<<<256, 1024, 0, stream>>>(msaR, ciw, cib, cow, cob, clg, clb,
                                    mbuf, nbuf);
    k_pair<<<512, 512, 0, stream>>>(mbuf, nbuf, pw, pb, pg, pbt, out);
}

// Round 2
// 144.395 us; speedup vs baseline: 1.0833x; 1.0336x over previous
//
#include <hip/hip_runtime.h>

#define LN_EPS 1e-5f

__device__ __forceinline__ float dot8(float4 a0, float4 a1, float4 b0, float4 b1) {
    return a0.x * b0.x + a0.y * b0.y + a0.z * b0.z + a0.w * b0.w +
           a1.x * b1.x + a1.y * b1.y + a1.z * b1.z + a1.w * b1.w;
}

// ---------------------------------------------------------------------------
// Kernel 1: embed + pos + row attention (64 bins) + residual + LN
// 512 blocks x 512 threads: block = (b, s, query-half). 2 blocks/CU -> two
// independent barrier domains per CU (phases pipeline across blocks).
// K/V computed for all 64 bins per block (cheap recompute); Q half per block.
// LN fused into write phase via 32-lane shuffle reductions (no serial wave).
// ---------------------------------------------------------------------------
__global__ __launch_bounds__(512, 4) void k_row(
    const float* __restrict__ ctcf, const float* __restrict__ hac,
    const float* __restrict__ me1,  const float* __restrict__ me3,
    const float* __restrict__ ew,   const float* __restrict__ eb,
    const float* __restrict__ pe,
    const float* __restrict__ w_in, const float* __restrict__ b_in,
    const float* __restrict__ w_out,const float* __restrict__ b_out,
    const float* __restrict__ ln_g, const float* __restrict__ ln_b,
    float* __restrict__ msaR)
{
    __shared__ float sx[64][33];        // x tile (residual source), all 64 bins
    __shared__ float sqkv[64 * 100];    // qkv rows, stride 100 (16B-aligned)
    __shared__ float so[32][33];        // attention output (this block's queries)

    const int blk = blockIdx.x;          // b*8 + s*2 + qh
    const int qh  = blk & 1;
    const int s   = (blk >> 1) & 3;
    const int b   = blk >> 3;
    const int qbase = qh * 32;
    const int tid = threadIdx.x;

    const float* chip = (s == 0) ? ctcf : (s == 1) ? hac : (s == 2) ? me1 : me3;

    for (int n = tid; n < 2048; n += 512) {
        int l = n >> 5, c = n & 31;
        sx[l][c] = chip[b * 64 + l] * ew[c] + eb[c] + pe[l * 32 + c];
    }
    __syncthreads();

    // qkv for ALL 64 rows (both halves need K/V; Q overlap is cheap)
    {
        const int l  = tid & 63;
        const int cg = tid >> 6;         // 0..7, wave-uniform
        float xr[32];
#pragma unroll
        for (int c = 0; c < 32; ++c) xr[c] = sx[l][c];
#pragma unroll
        for (int i = 0; i < 12; ++i) {
            int cc = i * 8 + cg;         // 0..95
            const float4* wr4 = (const float4*)&w_in[cc * 32];
            float acc = b_in[cc];
#pragma unroll
            for (int c4 = 0; c4 < 8; ++c4) {
                float4 wv = wr4[c4];
                acc += xr[c4 * 4 + 0] * wv.x + xr[c4 * 4 + 1] * wv.y +
                       xr[c4 * 4 + 2] * wv.z + xr[c4 * 4 + 3] * wv.w;
            }
            sqkv[l * 100 + cc] = acc;
        }
    }
    __syncthreads();

    // attention: thread (h = tid>>7, q = (tid>>2)&31, kc = tid&3)
    // kc in lane bits 0-1 -> 4-way key split merged with shfl_xor butterfly.
    // Key order rotated per kc so the 4 kc-groups hit distinct bank groups.
    {
        const int h  = tid >> 7;
        const int q  = (tid >> 2) & 31;
        const int kc = tid & 3;
        const int lq = qbase + q;
        const float4* qp = (const float4*)&sqkv[lq * 100 + h * 8];
        float4 q0 = qp[0], q1 = qp[1];
        const float scale = 0.35355339059327373f;  // 1/sqrt(8)
        float mrun = -1e30f, denom = 0.f, a[8];
#pragma unroll
        for (int dd = 0; dd < 8; ++dd) a[dd] = 0.f;
#pragma unroll
        for (int jj = 0; jj < 16; ++jj) {
            const int j = kc * 16 + ((jj + kc) & 15);   // bank-staggered
            const float4* kp = (const float4*)&sqkv[j * 100 + 32 + h * 8];
            float sc = dot8(q0, q1, kp[0], kp[1]) * scale;
            const float4* vp = (const float4*)&sqkv[j * 100 + 64 + h * 8];
            float4 v0 = vp[0], v1 = vp[1];
            float mnew = fmaxf(mrun, sc);
            float corr = __expf(mrun - mnew);
            float w = __expf(sc - mnew);
            denom = denom * corr + w;
            a[0] = a[0] * corr + w * v0.x;  a[1] = a[1] * corr + w * v0.y;
            a[2] = a[2] * corr + w * v0.z;  a[3] = a[3] * corr + w * v0.w;
            a[4] = a[4] * corr + w * v1.x;  a[5] = a[5] * corr + w * v1.y;
            a[6] = a[6] * corr + w * v1.z;  a[7] = a[7] * corr + w * v1.w;
            mrun = mnew;
        }
#pragma unroll
        for (int off = 1; off <= 2; off <<= 1) {
            float mo = __shfl_xor(mrun, off, 64);
            float dn = __shfl_xor(denom, off, 64);
            float mn = fmaxf(mrun, mo);
            float c1 = __expf(mrun - mn);
            float c2 = __expf(mo - mn);
            denom = denom * c1 + dn * c2;
#pragma unroll
            for (int dd = 0; dd < 8; ++dd) {
                float ao = __shfl_xor(a[dd], off, 64);
                a[dd] = a[dd] * c1 + ao * c2;
            }
            mrun = mn;
        }
        float inv = 1.f / denom;
        float r0, r1;
        if      (kc == 0) { r0 = a[0]; r1 = a[1]; }
        else if (kc == 1) { r0 = a[2]; r1 = a[3]; }
        else if (kc == 2) { r0 = a[4]; r1 = a[5]; }
        else              { r0 = a[6]; r1 = a[7]; }
        so[q][h * 8 + kc * 2 + 0] = r0 * inv;
        so[q][h * 8 + kc * 2 + 1] = r1 * inv;
    }
    __syncthreads();

    // out proj + residual -> sqkv rows 0..31 (2 outputs/thread)
    {
        const int lq2 = tid & 31;        // local query row
        const int cB  = tid >> 5;        // 0..15
        float orow[32];
#pragma unroll
        for (int k = 0; k < 32; ++k) orow[k] = so[lq2][k];
#pragma unroll
        for (int i = 0; i < 2; ++i) {
            int c = cB + i * 16;
            const float4* wr4 = (const float4*)&w_out[c * 32];
            float acc = b_out[c] + sx[qbase + lq2][c];
#pragma unroll
            for (int k4 = 0; k4 < 8; ++k4) {
                float4 wv = wr4[k4];
                acc += orow[k4 * 4 + 0] * wv.x + orow[k4 * 4 + 1] * wv.y +
                       orow[k4 * 4 + 2] * wv.z + orow[k4 * 4 + 3] * wv.w;
            }
            sqkv[lq2 * 100 + c] = acc;
        }
    }
    __syncthreads();

    // LN + write: lanes 0..31 of each half-wave hold one row's 32 channels
    {
        const int c = tid & 31;
#pragma unroll
        for (int p = 0; p < 2; ++p) {
            int r = p * 16 + (tid >> 5);           // 0..31 local row
            float v = sqkv[r * 100 + c];
            float s1 = v;
#pragma unroll
            for (int off = 16; off >= 1; off >>= 1) s1 += __shfl_xor(s1, off, 64);
            float mu = s1 * (1.f / 32.f);
            float d = v - mu;
            float s2 = d * d;
#pragma unroll
            for (int off = 16; off >= 1; off >>= 1) s2 += __shfl_xor(s2, off, 64);
            float rstd = rsqrtf(s2 * (1.f / 32.f) + LN_EPS);
            msaR[((b * 4 + s) * 64 + qbase + r) * 32 + c] = d * rstd * ln_g[c] + ln_b[c];
        }
    }
}

// ---------------------------------------------------------------------------
// Kernel 2: column attention (4 tracks) + residual + LN + track mean + norm
// 512 blocks x 512 threads: block = (b, 8-bin chunk) -> 32 rows (8 lo x 4 s).
// 2 blocks/CU. LN + mean + norm via shuffle reductions.
// ---------------------------------------------------------------------------
__global__ __launch_bounds__(512, 4) void k_col(
    const float* __restrict__ msaR,
    const float* __restrict__ w_in, const float* __restrict__ b_in,
    const float* __restrict__ w_out,const float* __restrict__ b_out,
    const float* __restrict__ ln_g, const float* __restrict__ ln_b,
    float* __restrict__ m_out, float* __restrict__ nrm_out)
{
    __shared__ float sx[32][33];        // rows keyed r = lo*4+s
    __shared__ float sqkv[32 * 100];
    __shared__ float so[32][33];        // attn out, later reused for LN'd v

    const int bx = blockIdx.x;           // 64 b x 8 chunks
    const int b  = bx >> 3;
    const int l0 = (bx & 7) * 8;
    const int tid = threadIdx.x;

    for (int n = tid; n < 1024; n += 512) {
        int r = n >> 5, c = n & 31;
        int lo = r >> 2, s = r & 3;
        sx[r][c] = msaR[((b * 4 + s) * 64 + l0 + lo) * 32 + c];
    }
    __syncthreads();

    // qkv: 32 rows x 96 cols, 6 outputs/thread
    {
        const int rr = tid & 31;
        const int cg = tid >> 5;         // 0..15
        float xr[32];
#pragma unroll
        for (int c = 0; c < 32; ++c) xr[c] = sx[rr][c];
#pragma unroll
        for (int i = 0; i < 6; ++i) {
            int cc = i * 16 + cg;
            const float4* wr4 = (const float4*)&w_in[cc * 32];
            float acc = b_in[cc];
#pragma unroll
            for (int c4 = 0; c4 < 8; ++c4) {
                float4 wv = wr4[c4];
                acc += xr[c4 * 4 + 0] * wv.x + xr[c4 * 4 + 1] * wv.y +
                       xr[c4 * 4 + 2] * wv.z + xr[c4 * 4 + 3] * wv.w;
            }
            sqkv[rr * 100 + cc] = acc;
        }
    }
    __syncthreads();

    // attention over 4 tracks: (lo = tid>>4, h = (tid>>2)&3, ia = tid&3)
    if (tid < 128) {
        const int lo = tid >> 4, h = (tid >> 2) & 3, ia = tid & 3;
        const float scale = 0.35355339059327373f;
        const float4* qp = (const float4*)&sqkv[(lo * 4 + ia) * 100 + h * 8];
        float4 q0 = qp[0], q1 = qp[1];
        float sc[4];
        float mx = -1e30f;
#pragma unroll
        for (int jj = 0; jj < 4; ++jj) {
            const float4* kp = (const float4*)&sqkv[(lo * 4 + jj) * 100 + 32 + h * 8];
            sc[jj] = dot8(q0, q1, kp[0], kp[1]) * scale;
            mx = fmaxf(mx, sc[jj]);
        }
        float den = 0.f;
#pragma unroll
        for (int jj = 0; jj < 4; ++jj) { sc[jj] = __expf(sc[jj] - mx); den += sc[jj]; }
        float inv = 1.f / den;
        float a[8];
#pragma unroll
        for (int dd = 0; dd < 8; ++dd) a[dd] = 0.f;
#pragma unroll
        for (int jj = 0; jj < 4; ++jj) {
            const float4* vp = (const float4*)&sqkv[(lo * 4 + jj) * 100 + 64 + h * 8];
            float4 v0 = vp[0], v1 = vp[1];
            float wgt = sc[jj];
            a[0] += wgt * v0.x;  a[1] += wgt * v0.y;
            a[2] += wgt * v0.z;  a[3] += wgt * v0.w;
            a[4] += wgt * v1.x;  a[5] += wgt * v1.y;
            a[6] += wgt * v1.z;  a[7] += wgt * v1.w;
        }
#pragma unroll
        for (int dd = 0; dd < 8; ++dd) so[lo * 4 + ia][h * 8 + dd] = a[dd] * inv;
    }
    __syncthreads();

    // out proj + residual (2 outputs/thread)
    {
        const int r2 = tid & 31;
        const int cB = tid >> 5;
        float orow[32];
#pragma unroll
        for (int k = 0; k < 32; ++k) orow[k] = so[r2][k];
#pragma unroll
        for (int i = 0; i < 2; ++i) {
            int c = cB + i * 16;
            const float4* wr4 = (const float4*)&w_out[c * 32];
            float acc = b_out[c] + sx[r2][c];
#pragma unroll
            for (int k4 = 0; k4 < 8; ++k4) {
                float4 wv = wr4[k4];
                acc += orow[k4 * 4 + 0] * wv.x + orow[k4 * 4 + 1] * wv.y +
                       orow[k4 * 4 + 2] * wv.z + orow[k4 * 4 + 3] * wv.w;
            }
            sqkv[r2 * 100 + c] = acc;
        }
    }
    __syncthreads();

    // LN normalize per row (pre-gamma), store v into so (shuffle reductions)
    {
        const int c = tid & 31;
#pragma unroll
        for (int p = 0; p < 2; ++p) {
            int r = p * 16 + (tid >> 5);
            float v = sqkv[r * 100 + c];
            float s1 = v;
#pragma unroll
            for (int off = 16; off >= 1; off >>= 1) s1 += __shfl_xor(s1, off, 64);
            float mu = s1 * (1.f / 32.f);
            float d = v - mu;
            float s2 = d * d;
#pragma unroll
            for (int off = 16; off >= 1; off >>= 1) s2 += __shfl_xor(s2, off, 64);
            float rstd = rsqrtf(s2 * (1.f / 32.f) + LN_EPS);
            so[r][c] = d * rstd;
        }
    }
    __syncthreads();

    // track mean (gamma/beta folded) + row norm via shuffle
    if (tid < 256) {
        const int lo = tid >> 5, c = tid & 31;
        float mval = 0.25f * (so[lo * 4 + 0][c] + so[lo * 4 + 1][c] +
                              so[lo * 4 + 2][c] + so[lo * 4 + 3][c]) * ln_g[c] + ln_b[c];
        m_out[(b * 64 + l0 + lo) * 32 + c] = mval;
        float q2 = mval * mval;
#pragma unroll
        for (int off = 16; off >= 1; off >>= 1) q2 += __shfl_xor(q2, off, 64);
        if (c == 0) nrm_out[b * 64 + l0 + lo] = sqrtf(q2);
    }
}

// ---------------------------------------------------------------------------
// Kernel 3: factorized outer-product + proj + LN + SiLU + transpose
// feat[b,i,j,cp] = (T_i[cp]·m_j)/(|m_i||m_j|) + pb;  T_i = pw·m_i
// 1024 blocks (b x 16 i-chunks of 4) x 256 threads -> 4 blocks/CU x 4 waves
// = 16 waves/CU with FOUR independent barrier domains per CU.
// T phase: 2 rems/thread (pw slice = 64 regs, coalesced loads, L2-hot).
// Out phase: wave w -> il = w, lane = j, 16 cp dots.
// ---------------------------------------------------------------------------
__global__ __launch_bounds__(256, 4) void k_pair(
    const float* __restrict__ m, const float* __restrict__ nrm,
    const float* __restrict__ pw, const float* __restrict__ pb,
    const float* __restrict__ pg, const float* __restrict__ pbeta,
    float* __restrict__ out)
{
    __shared__ float smj[64][36];       // stride 36 -> rows 16B-aligned
    __shared__ float sT[4 * 520];       // [il][rem], stride 520 (16B-aligned)
    __shared__ float snj[64];
    __shared__ float sbias[16], sgam[16], sbet[16];

    const int bx = blockIdx.x;          // 64 b x 16 i-chunks
    const int b  = bx >> 4;
    const int i0 = (bx & 15) * 4;
    const int tid = threadIdx.x;
    const int lane = tid & 63, w = tid >> 6;   // w = 0..3

    const int rem0 = tid, rem1 = tid + 256;    // rem = cp*32+d
    const float* pw0 = pw + (rem0 >> 5) * 1024 + (rem0 & 31);
    const float* pw1 = pw + (rem1 >> 5) * 1024 + (rem1 & 31);
    float w0[32], w1[32];
#pragma unroll
    for (int c = 0; c < 32; ++c) { w0[c] = pw0[c * 32]; w1[c] = pw1[c * 32]; }

    const float* mb = m + b * 2048;
    for (int n = tid; n < 2048; n += 256) smj[n >> 5][n & 31] = mb[n];
    if (tid < 64) snj[tid] = nrm[b * 64 + tid];
    if (tid < 16) {
        sbias[tid] = pb[tid];
        sgam[tid]  = pg[tid];
        sbet[tid]  = pbeta[tid];
    }
    __syncthreads();

    // T phase: thread computes T[il][rem0], T[il][rem1] for il = 0..3
#pragma unroll
    for (int il = 0; il < 4; ++il) {
        const float4* mr4 = (const float4*)&smj[i0 + il][0];  // b128 broadcast
        float a0 = 0.f, a1 = 0.f;
#pragma unroll
        for (int c4 = 0; c4 < 8; ++c4) {
            float4 mv = mr4[c4];
            a0 += mv.x * w0[c4 * 4 + 0] + mv.y * w0[c4 * 4 + 1] +
                  mv.z * w0[c4 * 4 + 2] + mv.w * w0[c4 * 4 + 3];
            a1 += mv.x * w1[c4 * 4 + 0] + mv.y * w1[c4 * 4 + 1] +
                  mv.z * w1[c4 * 4 + 2] + mv.w * w1[c4 * 4 + 3];
        }
        sT[il * 520 + rem0] = a0;       // lane-consecutive, conflict-free
        sT[il * 520 + rem1] = a1;
    }
    __syncthreads();

    // out phase: lane = j; wave w handles il = w
    const int j = lane;
    float mj[32];
    {
        const float4* mjp = (const float4*)&smj[j][0];
#pragma unroll
        for (int d4 = 0; d4 < 8; ++d4) {
            float4 t = mjp[d4];
            mj[d4 * 4 + 0] = t.x;  mj[d4 * 4 + 1] = t.y;
            mj[d4 * 4 + 2] = t.z;  mj[d4 * 4 + 3] = t.w;
        }
    }
    const float nj = snj[j];

    {
        const int il = w;
        const int ig = i0 + il;
        const float invn = 1.f / fmaxf(snj[ig] * nj, 1e-6f);
        float f[16];
#pragma unroll
        for (int cp = 0; cp < 16; ++cp) {
            const float4* tr = (const float4*)&sT[il * 520 + cp * 32]; // b128 bcast
            float acc = 0.f;
#pragma unroll
            for (int d4 = 0; d4 < 8; ++d4) {
                float4 tv = tr[d4];
                acc += tv.x * mj[d4 * 4 + 0] + tv.y * mj[d4 * 4 + 1] +
                       tv.z * mj[d4 * 4 + 2] + tv.w * mj[d4 * 4 + 3];
            }
            f[cp] = acc * invn + sbias[cp];
        }
        float mu = 0.f;
#pragma unroll
        for (int cp = 0; cp < 16; ++cp) mu += f[cp];
        mu *= (1.f / 16.f);
        float var = 0.f;
#pragma unroll
        for (int cp = 0; cp < 16; ++cp) { float d = f[cp] - mu; var += d * d; }
        var *= (1.f / 16.f);
        const float rstd = rsqrtf(var + LN_EPS);
#pragma unroll
        for (int cp = 0; cp < 16; ++cp) {
            float v = (f[cp] - mu) * rstd * sgam[cp] + sbet[cp];
            float sl = v / (1.f + __expf(-v));
            out[((b * 16 + cp) * 64 + ig) * 64 + j] = sl;
        }
    }
}

// ---------------------------------------------------------------------------
extern "C" void kernel_launch(void* const* d_in, const int* in_sizes, int n_in,
                              void* d_out, int out_size, void* d_ws, size_t ws_size,
                              hipStream_t stream) {
    const float* ctcf  = (const float*)d_in[0];
    const float* hac   = (const float*)d_in[1];
    const float* me1   = (const float*)d_in[2];
    const float* me3   = (const float*)d_in[3];
    const float* ew    = (const float*)d_in[4];
    const float* ebias = (const float*)d_in[5];
    const float* pe    = (const float*)d_in[6];
    const float* riw   = (const float*)d_in[7];
    const float* rib   = (const float*)d_in[8];
    const float* row_  = (const float*)d_in[9];
    const float* rob   = (const float*)d_in[10];
    const float* rlg   = (const float*)d_in[11];
    const float* rlb   = (const float*)d_in[12];
    const float* ciw   = (const float*)d_in[13];
    const float* cib   = (const float*)d_in[14];
    const float* cow   = (const float*)d_in[15];
    const float* cob   = (const float*)d_in[16];
    const float* clg   = (const float*)d_in[17];
    const float* clb   = (const float*)d_in[18];
    const float* pw    = (const float*)d_in[19];
    const float* pb    = (const float*)d_in[20];
    const float* pg    = (const float*)d_in[21];
    const float* pbt   = (const float*)d_in[22];

    float* out = (float*)d_out;

    // msaR (2 MB) borrows d_out (16 MB f32): fully consumed by k_col before
    // k_pair writes out (serial stream). m + norms in ws (~528 KB).
    float* msaR = (float*)d_out;
    float* mbuf = (float*)d_ws;                  // 64*64*32 floats
    float* nbuf = mbuf + 64 * 64 * 32;           // 64*64 floats

    k_row<<<512, 512, 0, stream>>>(ctcf, hac, me1, me3, ew, ebias, pe,
                                   riw, rib, row_, rob, rlg, rlb, msaR);
    k_col<<<512, 512, 0, stream>>>(msaR, ciw, cib, cow, cob, clg, clb,
                                   mbuf, nbuf);
    k_pair<<<1024, 256, 0, stream>>>(mbuf, nbuf, pw, pb, pg, pbt, out);
}

// Round 3
// 144.218 us; speedup vs baseline: 1.0847x; 1.0012x over previous
//
#include <hip/hip_runtime.h>

#define LN_EPS 1e-5f

__device__ __forceinline__ float dot8(float4 a0, float4 a1, float4 b0, float4 b1) {
    return a0.x * b0.x + a0.y * b0.y + a0.z * b0.z + a0.w * b0.w +
           a1.x * b1.x + a1.y * b1.y + a1.z * b1.z + a1.w * b1.w;
}

// ---------------------------------------------------------------------------
// Kernel 1: embed + pos + row attention (64 bins) + residual + LN
// 512 blocks x 512 threads: block = (b, s, query-half). 2 blocks/CU.
// Changes vs prev: embed fused into QKV phase (one fewer barrier, x stays in
// registers); weight-row addresses forced wave-uniform via readfirstlane so
// the backend can use s_load (SMEM pipe); attention switched to two-pass
// softmax (scores in regs -> shared max -> independent exps/FMAs) to cut the
// serial exp chain; merge needs no exp corrections (shared max).
// ---------------------------------------------------------------------------
__global__ __launch_bounds__(512, 4) void k_row(
    const float* __restrict__ ctcf, const float* __restrict__ hac,
    const float* __restrict__ me1,  const float* __restrict__ me3,
    const float* __restrict__ ew,   const float* __restrict__ eb,
    const float* __restrict__ pe,
    const float* __restrict__ w_in, const float* __restrict__ b_in,
    const float* __restrict__ w_out,const float* __restrict__ b_out,
    const float* __restrict__ ln_g, const float* __restrict__ ln_b,
    float* __restrict__ msaR)
{
    __shared__ float sx[64][33];        // residual source (written by wave 0)
    __shared__ float sqkv[64 * 100];    // qkv rows, stride 100 (16B-aligned)
    __shared__ float so[32][33];        // attention output (this block's queries)

    const int blk = blockIdx.x;          // b*8 + s*2 + qh
    const int qh  = blk & 1;
    const int s   = (blk >> 1) & 3;
    const int b   = blk >> 3;
    const int qbase = qh * 32;
    const int tid = threadIdx.x;

    const float* chip = (s == 0) ? ctcf : (s == 1) ? hac : (s == 2) ? me1 : me3;

    const int l  = tid & 63;
    const int cg = __builtin_amdgcn_readfirstlane(tid >> 6);  // 0..7 uniform

    // fused embed: x row straight into registers (redundant across waves, cheap)
    float xr[32];
    {
        const float cv = chip[b * 64 + l];
        const float4* pe4 = (const float4*)&pe[l * 32];
        const float4* ew4 = (const float4*)ew;
        const float4* eb4 = (const float4*)eb;
#pragma unroll
        for (int c4 = 0; c4 < 8; ++c4) {
            float4 pv = pe4[c4], e = ew4[c4], bb = eb4[c4];
            xr[c4 * 4 + 0] = cv * e.x + bb.x + pv.x;
            xr[c4 * 4 + 1] = cv * e.y + bb.y + pv.y;
            xr[c4 * 4 + 2] = cv * e.z + bb.z + pv.z;
            xr[c4 * 4 + 3] = cv * e.w + bb.w + pv.w;
        }
    }
    if (cg == 0) {                       // one wave stages the residual copy
#pragma unroll
        for (int c = 0; c < 32; ++c) sx[l][c] = xr[c];
    }

    // QKV: 12 outputs/thread; weight rows via uniform (SGPR) addresses
#pragma unroll
    for (int i = 0; i < 12; ++i) {
        const int cc = i * 8 + cg;       // 0..95, wave-uniform
        const float4* wr4 = (const float4*)&w_in[cc * 32];
        float acc = b_in[cc];
#pragma unroll
        for (int c4 = 0; c4 < 8; ++c4) {
            float4 wv = wr4[c4];
            acc += xr[c4 * 4 + 0] * wv.x + xr[c4 * 4 + 1] * wv.y +
                   xr[c4 * 4 + 2] * wv.z + xr[c4 * 4 + 3] * wv.w;
        }
        sqkv[l * 100 + cc] = acc;
    }
    __syncthreads();

    // attention, two-pass: thread (h = tid>>7, q = (tid>>2)&31, kc = tid&3)
    {
        const int h  = tid >> 7;
        const int q  = (tid >> 2) & 31;
        const int kc = tid & 3;
        const int lq = qbase + q;
        const float4* qp = (const float4*)&sqkv[lq * 100 + h * 8];
        float4 q0 = qp[0], q1 = qp[1];
        const float scale = 0.35355339059327373f;  // 1/sqrt(8)

        // pass 1: 16 scores into registers (independent)
        float sc[16];
#pragma unroll
        for (int jj = 0; jj < 16; ++jj) {
            const int j = kc * 16 + ((jj + kc) & 15);   // bank-staggered
            const float4* kp = (const float4*)&sqkv[j * 100 + 32 + h * 8];
            sc[jj] = dot8(q0, q1, kp[0], kp[1]) * scale;
        }
        // local max tree + cross-kc max (no exp on the critical path)
        float m0 = fmaxf(fmaxf(fmaxf(sc[0], sc[1]),  fmaxf(sc[2], sc[3])),
                         fmaxf(fmaxf(sc[4], sc[5]),  fmaxf(sc[6], sc[7])));
        float m1 = fmaxf(fmaxf(fmaxf(sc[8], sc[9]),  fmaxf(sc[10], sc[11])),
                         fmaxf(fmaxf(sc[12], sc[13]), fmaxf(sc[14], sc[15])));
        float mx = fmaxf(m0, m1);
        mx = fmaxf(mx, __shfl_xor(mx, 1, 64));
        mx = fmaxf(mx, __shfl_xor(mx, 2, 64));

        // pass 2: independent exps + weighted-V accumulation
        float den = 0.f, a[8];
#pragma unroll
        for (int dd = 0; dd < 8; ++dd) a[dd] = 0.f;
#pragma unroll
        for (int jj = 0; jj < 16; ++jj) {
            const int j = kc * 16 + ((jj + kc) & 15);
            float w = __expf(sc[jj] - mx);
            den += w;
            const float4* vp = (const float4*)&sqkv[j * 100 + 64 + h * 8];
            float4 v0 = vp[0], v1 = vp[1];
            a[0] += w * v0.x;  a[1] += w * v0.y;
            a[2] += w * v0.z;  a[3] += w * v0.w;
            a[4] += w * v1.x;  a[5] += w * v1.y;
            a[6] += w * v1.z;  a[7] += w * v1.w;
        }
        // merge across kc: plain sums (shared max -> no corrections)
#pragma unroll
        for (int off = 1; off <= 2; off <<= 1) {
            den += __shfl_xor(den, off, 64);
#pragma unroll
            for (int dd = 0; dd < 8; ++dd) a[dd] += __shfl_xor(a[dd], off, 64);
        }
        float inv = 1.f / den;
        float r0, r1;
        if      (kc == 0) { r0 = a[0]; r1 = a[1]; }
        else if (kc == 1) { r0 = a[2]; r1 = a[3]; }
        else if (kc == 2) { r0 = a[4]; r1 = a[5]; }
        else              { r0 = a[6]; r1 = a[7]; }
        so[q][h * 8 + kc * 2 + 0] = r0 * inv;
        so[q][h * 8 + kc * 2 + 1] = r1 * inv;
    }
    __syncthreads();

    // out proj + residual -> sqkv rows 0..31 (2 outputs/thread)
    {
        const int lq2 = tid & 31;
        const int cB  = tid >> 5;        // 0..15
        float orow[32];
#pragma unroll
        for (int k = 0; k < 32; ++k) orow[k] = so[lq2][k];
#pragma unroll
        for (int i = 0; i < 2; ++i) {
            int c = cB + i * 16;
            const float4* wr4 = (const float4*)&w_out[c * 32];
            float acc = b_out[c] + sx[qbase + lq2][c];
#pragma unroll
            for (int k4 = 0; k4 < 8; ++k4) {
                float4 wv = wr4[k4];
                acc += orow[k4 * 4 + 0] * wv.x + orow[k4 * 4 + 1] * wv.y +
                       orow[k4 * 4 + 2] * wv.z + orow[k4 * 4 + 3] * wv.w;
            }
            sqkv[lq2 * 100 + c] = acc;
        }
    }
    __syncthreads();

    // LN + write via 32-lane shuffle reductions
    {
        const int c = tid & 31;
#pragma unroll
        for (int p = 0; p < 2; ++p) {
            int r = p * 16 + (tid >> 5);           // 0..31 local row
            float v = sqkv[r * 100 + c];
            float s1 = v;
#pragma unroll
            for (int off = 16; off >= 1; off >>= 1) s1 += __shfl_xor(s1, off, 64);
            float mu = s1 * (1.f / 32.f);
            float d = v - mu;
            float s2 = d * d;
#pragma unroll
            for (int off = 16; off >= 1; off >>= 1) s2 += __shfl_xor(s2, off, 64);
            float rstd = rsqrtf(s2 * (1.f / 32.f) + LN_EPS);
            msaR[((b * 4 + s) * 64 + qbase + r) * 32 + c] = d * rstd * ln_g[c] + ln_b[c];
        }
    }
}

// ---------------------------------------------------------------------------
// Kernel 2: column attention (4 tracks) + residual + LN + track mean + norm
// 1024 blocks x 256 threads: block = (b, 4-bin chunk) -> 16 rows (4 lo x 4 s).
// 4 blocks/CU x 4 waves = 16 waves/CU with FOUR independent barrier domains.
// ---------------------------------------------------------------------------
__global__ __launch_bounds__(256, 4) void k_col(
    const float* __restrict__ msaR,
    const float* __restrict__ w_in, const float* __restrict__ b_in,
    const float* __restrict__ w_out,const float* __restrict__ b_out,
    const float* __restrict__ ln_g, const float* __restrict__ ln_b,
    float* __restrict__ m_out, float* __restrict__ nrm_out)
{
    __shared__ float sx[16][33];        // rows keyed r = lo*4+s
    __shared__ float sqkv[16 * 100];
    __shared__ float so[16][33];        // attn out, later reused for LN'd v

    const int bx = blockIdx.x;           // 64 b x 16 chunks
    const int b  = bx >> 4;
    const int l0 = (bx & 15) * 4;
    const int tid = threadIdx.x;

    for (int n = tid; n < 512; n += 256) {
        int r = n >> 5, c = n & 31;      // r = lo*4+s
        int lo = r >> 2, s = r & 3;
        sx[r][c] = msaR[((b * 4 + s) * 64 + l0 + lo) * 32 + c];
    }
    __syncthreads();

    // qkv: 16 rows x 96 cols, 6 outputs/thread
    {
        const int rr = tid & 15;
        const int cg = tid >> 4;         // 0..15
        float xr[32];
#pragma unroll
        for (int c = 0; c < 32; ++c) xr[c] = sx[rr][c];
#pragma unroll
        for (int i = 0; i < 6; ++i) {
            int cc = i * 16 + cg;
            const float4* wr4 = (const float4*)&w_in[cc * 32];
            float acc = b_in[cc];
#pragma unroll
            for (int c4 = 0; c4 < 8; ++c4) {
                float4 wv = wr4[c4];
                acc += xr[c4 * 4 + 0] * wv.x + xr[c4 * 4 + 1] * wv.y +
                       xr[c4 * 4 + 2] * wv.z + xr[c4 * 4 + 3] * wv.w;
            }
            sqkv[rr * 100 + cc] = acc;
        }
    }
    __syncthreads();

    // attention over 4 tracks: 64 units (lo = tid>>4, h = (tid>>2)&3, ia = tid&3)
    if (tid < 64) {
        const int lo = tid >> 4, h = (tid >> 2) & 3, ia = tid & 3;
        const float scale = 0.35355339059327373f;
        const float4* qp = (const float4*)&sqkv[(lo * 4 + ia) * 100 + h * 8];
        float4 q0 = qp[0], q1 = qp[1];
        float sc[4];
        float mx = -1e30f;
#pragma unroll
        for (int jj = 0; jj < 4; ++jj) {
            const float4* kp = (const float4*)&sqkv[(lo * 4 + jj) * 100 + 32 + h * 8];
            sc[jj] = dot8(q0, q1, kp[0], kp[1]) * scale;
            mx = fmaxf(mx, sc[jj]);
        }
        float den = 0.f;
#pragma unroll
        for (int jj = 0; jj < 4; ++jj) { sc[jj] = __expf(sc[jj] - mx); den += sc[jj]; }
        float inv = 1.f / den;
        float a[8];
#pragma unroll
        for (int dd = 0; dd < 8; ++dd) a[dd] = 0.f;
#pragma unroll
        for (int jj = 0; jj < 4; ++jj) {
            const float4* vp = (const float4*)&sqkv[(lo * 4 + jj) * 100 + 64 + h * 8];
            float4 v0 = vp[0], v1 = vp[1];
            float wgt = sc[jj];
            a[0] += wgt * v0.x;  a[1] += wgt * v0.y;
            a[2] += wgt * v0.z;  a[3] += wgt * v0.w;
            a[4] += wgt * v1.x;  a[5] += wgt * v1.y;
            a[6] += wgt * v1.z;  a[7] += wgt * v1.w;
        }
#pragma unroll
        for (int dd = 0; dd < 8; ++dd) so[lo * 4 + ia][h * 8 + dd] = a[dd] * inv;
    }
    __syncthreads();

    // out proj + residual (2 outputs/thread)
    {
        const int r2 = tid & 15;
        const int cB = tid >> 4;         // 0..15
        float orow[32];
#pragma unroll
        for (int k = 0; k < 32; ++k) orow[k] = so[r2][k];
#pragma unroll
        for (int i = 0; i < 2; ++i) {
            int c = cB + i * 16;
            const float4* wr4 = (const float4*)&w_out[c * 32];
            float acc = b_out[c] + sx[r2][c];
#pragma unroll
            for (int k4 = 0; k4 < 8; ++k4) {
                float4 wv = wr4[k4];
                acc += orow[k4 * 4 + 0] * wv.x + orow[k4 * 4 + 1] * wv.y +
                       orow[k4 * 4 + 2] * wv.z + orow[k4 * 4 + 3] * wv.w;
            }
            sqkv[r2 * 100 + c] = acc;
        }
    }
    __syncthreads();

    // LN normalize per row (pre-gamma), store into so (shuffle reductions)
    {
        const int c = tid & 31;
#pragma unroll
        for (int p = 0; p < 2; ++p) {
            int r = p * 8 + (tid >> 5);  // 0..15
            float v = sqkv[r * 100 + c];
            float s1 = v;
#pragma unroll
            for (int off = 16; off >= 1; off >>= 1) s1 += __shfl_xor(s1, off, 64);
            float mu = s1 * (1.f / 32.f);
            float d = v - mu;
            float s2 = d * d;
#pragma unroll
            for (int off = 16; off >= 1; off >>= 1) s2 += __shfl_xor(s2, off, 64);
            float rstd = rsqrtf(s2 * (1.f / 32.f) + LN_EPS);
            so[r][c] = d * rstd;
        }
    }
    __syncthreads();

    // track mean (gamma/beta folded) + row norm via shuffle: 4 lo x 32 c
    if (tid < 128) {
        const int lo = tid >> 5, c = tid & 31;
        float mval = 0.25f * (so[lo * 4 + 0][c] + so[lo * 4 + 1][c] +
                              so[lo * 4 + 2][c] + so[lo * 4 + 3][c]) * ln_g[c] + ln_b[c];
        m_out[(b * 64 + l0 + lo) * 32 + c] = mval;
        float q2 = mval * mval;
#pragma unroll
        for (int off = 16; off >= 1; off >>= 1) q2 += __shfl_xor(q2, off, 64);
        if (c == 0) nrm_out[b * 64 + l0 + lo] = sqrtf(q2);
    }
}

// ---------------------------------------------------------------------------
// Kernel 3: factorized outer-product + proj + LN + SiLU + transpose
// feat[b,i,j,cp] = (T_i[cp]·m_j)/(|m_i||m_j|) + pb;  T_i = pw·m_i
// 1024 blocks (b x 16 i-chunks of 4) x 256 threads -> 4 blocks/CU x 4 waves.
// ---------------------------------------------------------------------------
__global__ __launch_bounds__(256, 4) void k_pair(
    const float* __restrict__ m, const float* __restrict__ nrm,
    const float* __restrict__ pw, const float* __restrict__ pb,
    const float* __restrict__ pg, const float* __restrict__ pbeta,
    float* __restrict__ out)
{
    __shared__ float smj[64][36];       // stride 36 -> rows 16B-aligned
    __shared__ float sT[4 * 520];       // [il][rem], stride 520 (16B-aligned)
    __shared__ float snj[64];
    __shared__ float sbias[16], sgam[16], sbet[16];

    const int bx = blockIdx.x;          // 64 b x 16 i-chunks
    const int b  = bx >> 4;
    const int i0 = (bx & 15) * 4;
    const int tid = threadIdx.x;
    const int lane = tid & 63, w = tid >> 6;   // w = 0..3

    const int rem0 = tid, rem1 = tid + 256;    // rem = cp*32+d
    const float* pw0 = pw + (rem0 >> 5) * 1024 + (rem0 & 31);
    const float* pw1 = pw + (rem1 >> 5) * 1024 + (rem1 & 31);
    float w0[32], w1[32];
#pragma unroll
    for (int c = 0; c < 32; ++c) { w0[c] = pw0[c * 32]; w1[c] = pw1[c * 32]; }

    const float* mb = m + b * 2048;
    for (int n = tid; n < 2048; n += 256) smj[n >> 5][n & 31] = mb[n];
    if (tid < 64) snj[tid] = nrm[b * 64 + tid];
    if (tid < 16) {
        sbias[tid] = pb[tid];
        sgam[tid]  = pg[tid];
        sbet[tid]  = pbeta[tid];
    }
    __syncthreads();

    // T phase: thread computes T[il][rem0], T[il][rem1] for il = 0..3
#pragma unroll
    for (int il = 0; il < 4; ++il) {
        const float4* mr4 = (const float4*)&smj[i0 + il][0];  // b128 broadcast
        float a0 = 0.f, a1 = 0.f;
#pragma unroll
        for (int c4 = 0; c4 < 8; ++c4) {
            float4 mv = mr4[c4];
            a0 += mv.x * w0[c4 * 4 + 0] + mv.y * w0[c4 * 4 + 1] +
                  mv.z * w0[c4 * 4 + 2] + mv.w * w0[c4 * 4 + 3];
            a1 += mv.x * w1[c4 * 4 + 0] + mv.y * w1[c4 * 4 + 1] +
                  mv.z * w1[c4 * 4 + 2] + mv.w * w1[c4 * 4 + 3];
        }
        sT[il * 520 + rem0] = a0;       // lane-consecutive, conflict-free
        sT[il * 520 + rem1] = a1;
    }
    __syncthreads();

    // out phase: lane = j; wave w handles il = w
    const int j = lane;
    float mj[32];
    {
        const float4* mjp = (const float4*)&smj[j][0];
#pragma unroll
        for (int d4 = 0; d4 < 8; ++d4) {
            float4 t = mjp[d4];
            mj[d4 * 4 + 0] = t.x;  mj[d4 * 4 + 1] = t.y;
            mj[d4 * 4 + 2] = t.z;  mj[d4 * 4 + 3] = t.w;
        }
    }
    const float nj = snj[j];

    {
        const int il = w;
        const int ig = i0 + il;
        const float invn = 1.f / fmaxf(snj[ig] * nj, 1e-6f);
        float f[16];
#pragma unroll
        for (int cp = 0; cp < 16; ++cp) {
            const float4* tr = (const float4*)&sT[il * 520 + cp * 32]; // b128 bcast
            float acc = 0.f;
#pragma unroll
            for (int d4 = 0; d4 < 8; ++d4) {
                float4 tv = tr[d4];
                acc += tv.x * mj[d4 * 4 + 0] + tv.y * mj[d4 * 4 + 1] +
                       tv.z * mj[d4 * 4 + 2] + tv.w * mj[d4 * 4 + 3];
            }
            f[cp] = acc * invn + sbias[cp];
        }
        float mu = 0.f;
#pragma unroll
        for (int cp = 0; cp < 16; ++cp) mu += f[cp];
        mu *= (1.f / 16.f);
        float var = 0.f;
#pragma unroll
        for (int cp = 0; cp < 16; ++cp) { float d = f[cp] - mu; var += d * d; }
        var *= (1.f / 16.f);
        const float rstd = rsqrtf(var + LN_EPS);
#pragma unroll
        for (int cp = 0; cp < 16; ++cp) {
            float v = (f[cp] - mu) * rstd * sgam[cp] + sbet[cp];
            float sl = v / (1.f + __expf(-v));
            out[((b * 16 + cp) * 64 + ig) * 64 + j] = sl;
        }
    }
}

// ---------------------------------------------------------------------------
extern "C" void kernel_launch(void* const* d_in, const int* in_sizes, int n_in,
                              void* d_out, int out_size, void* d_ws, size_t ws_size,
                              hipStream_t stream) {
    const float* ctcf  = (const float*)d_in[0];
    const float* hac   = (const float*)d_in[1];
    const float* me1   = (const float*)d_in[2];
    const float* me3   = (const float*)d_in[3];
    const float* ew    = (const float*)d_in[4];
    const float* ebias = (const float*)d_in[5];
    const float* pe    = (const float*)d_in[6];
    const float* riw   = (const float*)d_in[7];
    const float* rib   = (const float*)d_in[8];
    const float* row_  = (const float*)d_in[9];
    const float* rob   = (const float*)d_in[10];
    const float* rlg   = (const float*)d_in[11];
    const float* rlb   = (const float*)d_in[12];
    const float* ciw   = (const float*)d_in[13];
    const float* cib   = (const float*)d_in[14];
    const float* cow   = (const float*)d_in[15];
    const float* cob   = (const float*)d_in[16];
    const float* clg   = (const float*)d_in[17];
    const float* clb   = (const float*)d_in[18];
    const float* pw    = (const float*)d_in[19];
    const float* pb    = (const float*)d_in[20];
    const float* pg    = (const float*)d_in[21];
    const float* pbt   = (const float*)d_in[22];

    float* out = (float*)d_out;

    // msaR (2 MB) borrows d_out (16 MB f32): fully consumed by k_col before
    // k_pair writes out (serial stream). m + norms in ws (~528 KB).
    float* msaR = (float*)d_out;
    float* mbuf = (float*)d_ws;                  // 64*64*32 floats
    float* nbuf = mbuf + 64 * 64 * 32;           // 64*64 floats

    k_row<<<512, 512, 0, stream>>>(ctcf, hac, me1, me3, ew, ebias, pe,
                                   riw, rib, row_, rob, rlg, rlb, msaR);
    k_col<<<1024, 256, 0, stream>>>(msaR, ciw, cib, cow, cob, clg, clb,
                                    mbuf, nbuf);
    k_pair<<<1024, 256, 0, stream>>>(mbuf, nbuf, pw, pb, pg, pbt, out);
}